// Round 4
// baseline (1417.318 us; speedup 1.0000x reference)
//
#include <hip/hip_runtime.h>
#include <cstdint>

#define NROW 66560   // 2*NX + J rows through both MLPs
#define NXP  32768   // nx
#define NV   1024    // J
#define FD   100     // dn output dim
#define GD   28      // input / an output dim
#define HD   300     // hidden dim
#define HP   320     // padded hidden dim
#define ASTR 328     // LDS activation stride (u16) — 2-way-only bank alias

typedef unsigned short u16;
typedef __bf16 bf16x8 __attribute__((ext_vector_type(8)));
typedef float  f32x4  __attribute__((ext_vector_type(4)));

__device__ inline u16 f2bf(float x) {
  unsigned u = __builtin_bit_cast(unsigned, x);
  unsigned r = (u + 0x7FFF + ((u >> 16) & 1)) >> 16;
  return (u16)r;
}
__device__ inline float bf2f(u16 h) {
  unsigned u = ((unsigned)h) << 16;
  return __builtin_bit_cast(float, u);
}

// ---------------------------------------------------------------------------
// Prep: assemble [X;Y;V] rows, emit bf16 hi/lo planes (K padded 28->32) and
// fp32 copy (for the an-MLP residual).
// ---------------------------------------------------------------------------
__global__ __launch_bounds__(256) void prep_x(
    const float* __restrict__ XY, const float* __restrict__ V,
    u16* __restrict__ Xhi, u16* __restrict__ Xlo, float* __restrict__ Xf)
{
  int gid = blockIdx.x * 256 + threadIdx.x;   // NROW*32 total
  int row = gid >> 5, k = gid & 31;
  if (row >= NROW) return;
  float v = 0.f;
  if (k < GD) v = (row < 2 * NXP) ? XY[(size_t)row * GD + k]
                                  : V[(size_t)(row - 2 * NXP) * GD + k];
  u16 hi = f2bf(v);
  u16 lo = f2bf(v - bf2f(hi));
  Xhi[(size_t)row * 32 + k] = hi;
  Xlo[(size_t)row * 32 + k] = lo;
  if (k < GD) Xf[(size_t)row * GD + k] = v;
}

// ---------------------------------------------------------------------------
// Prep: transpose + split + zero-pad all 12 weight matrices. Wt[m][k] layout.
// ---------------------------------------------------------------------------
struct WDesc { const float* W; u16* hi; u16* lo; int K, M, Kpad, Mpad; };
struct WAll  { WDesc d[12]; };

__global__ __launch_bounds__(256) void prep_w(WAll wa)
{
  WDesc d = wa.d[blockIdx.y];
  int gid = blockIdx.x * 256 + threadIdx.x;
  if (gid >= d.Kpad * d.Mpad) return;
  int m = gid / d.Kpad, k = gid - m * d.Kpad;
  float v = (k < d.K && m < d.M) ? d.W[(size_t)k * d.M + m] : 0.f;
  u16 hi = f2bf(v);
  u16 lo = f2bf(v - bf2f(hi));
  d.hi[(size_t)m * d.Kpad + k] = hi;
  d.lo[(size_t)m * d.Kpad + k] = lo;
}

// ---------------------------------------------------------------------------
// Fused 12-layer MLP. 32 samples/block, 128 threads (2 waves).
// A-operand = weights (streamed global->reg, no LDS, no k-loop barriers).
// B-operand = activations (LDS hi/lo planes, rewritten in-place per layer).
// C layout: col(lane&15)=sample, row(quad*4+r)=feature (4 consecutive)
//   -> epilogue packs 4 feats into one ds_write_b64 per plane,
//   -> final layers store float4 to f_all/g_all.
// 3 MFMAs per product (bf16x3 split: Ah*Bh + Al*Bh + Ah*Bl).
// ---------------------------------------------------------------------------
struct BiasAll { const float* b[12]; };

template<int MT, int KCH, int KP>
__device__ __forceinline__ void stage_mm(
    const u16* __restrict__ Wh, const u16* __restrict__ Wl,
    const u16* Bh, const u16* Bl, int bstr,
    f32x4 (*acc)[2], int wave, int m16, int quad)
{
#pragma unroll
  for (int mt = 0; mt < MT; ++mt)
#pragma unroll
    for (int nt = 0; nt < 2; ++nt) acc[mt][nt] = (f32x4)0.f;
  for (int ch = 0; ch < KCH; ++ch) {
    const int k0 = ch * 32;
    bf16x8 bh[2], bl[2];
#pragma unroll
    for (int nt = 0; nt < 2; ++nt) {
      bh[nt] = *reinterpret_cast<const bf16x8*>(&Bh[(nt * 16 + m16) * bstr + k0 + quad * 8]);
      bl[nt] = *reinterpret_cast<const bf16x8*>(&Bl[(nt * 16 + m16) * bstr + k0 + quad * 8]);
    }
#pragma unroll
    for (int mt = 0; mt < MT; ++mt) {
      int feat = (wave * MT + mt) * 16 + m16;
      bf16x8 ah = *reinterpret_cast<const bf16x8*>(&Wh[(size_t)feat * KP + k0 + quad * 8]);
      bf16x8 al = *reinterpret_cast<const bf16x8*>(&Wl[(size_t)feat * KP + k0 + quad * 8]);
#pragma unroll
      for (int nt = 0; nt < 2; ++nt) {
        acc[mt][nt] = __builtin_amdgcn_mfma_f32_16x16x32_bf16(ah, bh[nt], acc[mt][nt], 0, 0, 0);
        acc[mt][nt] = __builtin_amdgcn_mfma_f32_16x16x32_bf16(al, bh[nt], acc[mt][nt], 0, 0, 0);
        acc[mt][nt] = __builtin_amdgcn_mfma_f32_16x16x32_bf16(ah, bl[nt], acc[mt][nt], 0, 0, 0);
      }
    }
  }
}

template<int MT>
__device__ __forceinline__ void epi_hidden(
    f32x4 (*acc)[2], const float* __restrict__ bias,
    u16* Ah, u16* Al, int wave, int m16, int quad)
{
#pragma unroll
  for (int mt = 0; mt < MT; ++mt) {
    int featb = (wave * MT + mt) * 16 + quad * 4;
#pragma unroll
    for (int nt = 0; nt < 2; ++nt) {
      int samp = nt * 16 + m16;
      ushort4 h4, l4;
#pragma unroll
      for (int r = 0; r < 4; ++r) {
        int feat = featb + r;
        float x = acc[mt][nt][r] + (feat < HD ? bias[feat] : 0.f);
        x = fmaxf(x, 0.f);
        u16 h = f2bf(x);
        u16 l = f2bf(x - bf2f(h));
        reinterpret_cast<u16*>(&h4)[r] = h;
        reinterpret_cast<u16*>(&l4)[r] = l;
      }
      *reinterpret_cast<ushort4*>(&Ah[samp * ASTR + featb]) = h4;
      *reinterpret_cast<ushort4*>(&Al[samp * ASTR + featb]) = l4;
    }
  }
}

__global__ __launch_bounds__(128, 2) void mlp_fused(
    const u16* __restrict__ Xhi, const u16* __restrict__ Xlo,
    const float* __restrict__ Xf,
    const u16* __restrict__ Whi, const u16* __restrict__ Wlo,
    BiasAll bp, float* __restrict__ f_all, float* __restrict__ g_all)
{
  __shared__ u16 aH[32 * ASTR], aL[32 * ASTR];
  __shared__ u16 inH[32 * 40],  inL[32 * 40];
  const int tid  = threadIdx.x;
  const int wave = tid >> 6, lane = tid & 63;
  const int m16  = lane & 15, quad = lane >> 4;
  const int row0 = blockIdx.x * 32;

  // stage input planes (32 rows x 32 k): 128 uint4 per plane, 1/thread
  {
    int r = tid >> 2, kc = tid & 3;
    uint4 h = *reinterpret_cast<const uint4*>(&Xhi[(size_t)(row0 + r) * 32 + kc * 8]);
    uint4 l = *reinterpret_cast<const uint4*>(&Xlo[(size_t)(row0 + r) * 32 + kc * 8]);
    *reinterpret_cast<uint4*>(&inH[r * 40 + kc * 8]) = h;
    *reinterpret_cast<uint4*>(&inL[r * 40 + kc * 8]) = l;
  }
  __syncthreads();

  auto slotH = [&](int s) { return Whi + (size_t)s * HP * HP; };
  auto slotL = [&](int s) { return Wlo + (size_t)s * HP * HP; };

  f32x4 acc[10][2];

  // ---- dn MLP ----
  stage_mm<10, 1, 32>(slotH(0), slotL(0), inH, inL, 40, acc, wave, m16, quad);
  epi_hidden<10>(acc, bp.b[0], aH, aL, wave, m16, quad);   // first aH write, no prior readers
  __syncthreads();
#pragma unroll 1
  for (int s = 1; s <= 4; ++s) {
    stage_mm<10, 10, HP>(slotH(s), slotL(s), aH, aL, ASTR, acc, wave, m16, quad);
    __syncthreads();   // all reads of aH done
    epi_hidden<10>(acc, bp.b[s], aH, aL, wave, m16, quad);
    __syncthreads();   // writes visible
  }
  stage_mm<4, 10, HP>(slotH(5), slotL(5), aH, aL, ASTR, acc, wave, m16, quad);
  {
    const float* b5 = bp.b[5];
#pragma unroll
    for (int mt = 0; mt < 4; ++mt) {
      int c = (wave * 4 + mt) * 16 + quad * 4;
      if (c < FD) {
#pragma unroll
        for (int nt = 0; nt < 2; ++nt) {
          int samp = nt * 16 + m16;
          float4 v;
          v.x = acc[mt][nt][0] + b5[c + 0];
          v.y = acc[mt][nt][1] + b5[c + 1];
          v.z = acc[mt][nt][2] + b5[c + 2];
          v.w = acc[mt][nt][3] + b5[c + 3];
          *reinterpret_cast<float4*>(&f_all[(size_t)(row0 + samp) * FD + c]) = v;
        }
      }
    }
  }
  __syncthreads();   // stage-5 reads of aH complete before an-MLP overwrites

  // ---- an MLP ----
  stage_mm<10, 1, 32>(slotH(6), slotL(6), inH, inL, 40, acc, wave, m16, quad);
  epi_hidden<10>(acc, bp.b[6], aH, aL, wave, m16, quad);
  __syncthreads();
#pragma unroll 1
  for (int s = 7; s <= 10; ++s) {
    stage_mm<10, 10, HP>(slotH(s), slotL(s), aH, aL, ASTR, acc, wave, m16, quad);
    __syncthreads();
    epi_hidden<10>(acc, bp.b[s], aH, aL, wave, m16, quad);
    __syncthreads();
  }
  stage_mm<1, 10, HP>(slotH(11), slotL(11), aH, aL, ASTR, acc, wave, m16, quad);
  {
    const float* b11 = bp.b[11];
    int c = wave * 16 + quad * 4;
    if (c < GD) {
#pragma unroll
      for (int nt = 0; nt < 2; ++nt) {
        int samp = nt * 16 + m16;
        float4 rv = *reinterpret_cast<const float4*>(&Xf[(size_t)(row0 + samp) * GD + c]);
        float4 v;
        v.x = acc[0][nt][0] + b11[c + 0] + rv.x;
        v.y = acc[0][nt][1] + b11[c + 1] + rv.y;
        v.z = acc[0][nt][2] + b11[c + 2] + rv.z;
        v.w = acc[0][nt][3] + b11[c + 3] + rv.w;
        *reinterpret_cast<float4*>(&g_all[(size_t)(row0 + samp) * GD + c]) = v;
      }
    }
  }
}

// ---------------------------------------------------------------------------
// Row squared-norms of f_all (100 dims) and g_all (28 dims). One wave per row.
// ---------------------------------------------------------------------------
__global__ __launch_bounds__(256) void norms_k(
    const float* __restrict__ f_all, const float* __restrict__ g_all,
    float* __restrict__ fn, float* __restrict__ gn)
{
  int wave = threadIdx.x >> 6, lane = threadIdx.x & 63;
  int row = blockIdx.x * 4 + wave;
  const float* f = f_all + (size_t)row * FD;
  const float* g = g_all + (size_t)row * GD;
  float s = f[lane] * f[lane];
  if (lane < FD - 64) { float t = f[lane + 64]; s += t * t; }
  float sg = 0.f;
  if (lane < GD) { float t = g[lane]; sg = t * t; }
#pragma unroll
  for (int m = 32; m >= 1; m >>= 1) { s += __shfl_xor(s, m); sg += __shfl_xor(sg, m); }
  if (lane == 0) { fn[row] = s; gn[row] = sg; }
}

// ---------------------------------------------------------------------------
// Pass 1: fused pdist2 + kernel + fm write + colsum/ss partial reductions.
// ---------------------------------------------------------------------------
__global__ __launch_bounds__(256) void dist1_k(
    const float* __restrict__ f_all, const float* __restrict__ g_all,
    const float* __restrict__ fn, const float* __restrict__ gn,
    const float* __restrict__ p_eps, const float* __restrict__ p_sig,
    const float* __restrict__ p_sig0, const float* __restrict__ p_cst,
    float* __restrict__ fm, double* __restrict__ colsum,
    double* __restrict__ ss_parts)
{
  __shared__ float Xs[GD][68], Ys[GD][68], Vs[GD][68];
  __shared__ float fnX[64], fnY[64], fnV[64], gnX[64], gnY[64], gnV[64];
  __shared__ float red[16][68];
  __shared__ float ssred[4];
  const int tid = threadIdx.x;
  const int tx = tid & 15, ty = tid >> 4;
  const int i0 = blockIdx.x * 64, j0 = blockIdx.y * 64;

  if (tid < 64) {
    fnX[tid] = fn[i0 + tid]; fnY[tid] = fn[NXP + i0 + tid]; fnV[tid] = fn[2 * NXP + j0 + tid];
    gnX[tid] = gn[i0 + tid]; gnY[tid] = gn[NXP + i0 + tid]; gnV[tid] = gn[2 * NXP + j0 + tid];
  }

  float Sxf[4][4] = {}, Syf[4][4] = {}, Sxg[4][4] = {}, Syg[4][4] = {};
  const float* fX = f_all;
  const float* fY = f_all + (size_t)NXP * FD;
  const float* fV = f_all + (size_t)2 * NXP * FD;
  const float* gX = g_all;
  const float* gY = g_all + (size_t)NXP * GD;
  const float* gV = g_all + (size_t)2 * NXP * GD;

  for (int k0 = 0; k0 < FD; k0 += 20) {
    __syncthreads();
    for (int l = tid; l < 320; l += 256) {
      int r = l / 5, kc = l % 5;
      float4 a = *reinterpret_cast<const float4*>(&fX[(size_t)(i0 + r) * FD + k0 + kc * 4]);
      float4 b = *reinterpret_cast<const float4*>(&fY[(size_t)(i0 + r) * FD + k0 + kc * 4]);
      float4 c = *reinterpret_cast<const float4*>(&fV[(size_t)(j0 + r) * FD + k0 + kc * 4]);
      Xs[kc*4+0][r]=a.x; Xs[kc*4+1][r]=a.y; Xs[kc*4+2][r]=a.z; Xs[kc*4+3][r]=a.w;
      Ys[kc*4+0][r]=b.x; Ys[kc*4+1][r]=b.y; Ys[kc*4+2][r]=b.z; Ys[kc*4+3][r]=b.w;
      Vs[kc*4+0][r]=c.x; Vs[kc*4+1][r]=c.y; Vs[kc*4+2][r]=c.z; Vs[kc*4+3][r]=c.w;
    }
    __syncthreads();
#pragma unroll
    for (int kk = 0; kk < 20; ++kk) {
      float4 ax = *reinterpret_cast<const float4*>(&Xs[kk][ty * 4]);
      float4 ay = *reinterpret_cast<const float4*>(&Ys[kk][ty * 4]);
      float4 bv = *reinterpret_cast<const float4*>(&Vs[kk][tx * 4]);
      float axv[4] = {ax.x, ax.y, ax.z, ax.w};
      float ayv[4] = {ay.x, ay.y, ay.z, ay.w};
      float bvv[4] = {bv.x, bv.y, bv.z, bv.w};
#pragma unroll
      for (int i = 0; i < 4; ++i)
#pragma unroll
        for (int j = 0; j < 4; ++j) {
          Sxf[i][j] = fmaf(axv[i], bvv[j], Sxf[i][j]);
          Syf[i][j] = fmaf(ayv[i], bvv[j], Syf[i][j]);
        }
    }
  }

  __syncthreads();
  for (int l = tid; l < 448; l += 256) {
    int r = l / 7, kc = l % 7;
    float4 a = *reinterpret_cast<const float4*>(&gX[(size_t)(i0 + r) * GD + kc * 4]);
    float4 b = *reinterpret_cast<const float4*>(&gY[(size_t)(i0 + r) * GD + kc * 4]);
    float4 c = *reinterpret_cast<const float4*>(&gV[(size_t)(j0 + r) * GD + kc * 4]);
    Xs[kc*4+0][r]=a.x; Xs[kc*4+1][r]=a.y; Xs[kc*4+2][r]=a.z; Xs[kc*4+3][r]=a.w;
    Ys[kc*4+0][r]=b.x; Ys[kc*4+1][r]=b.y; Ys[kc*4+2][r]=b.z; Ys[kc*4+3][r]=b.w;
    Vs[kc*4+0][r]=c.x; Vs[kc*4+1][r]=c.y; Vs[kc*4+2][r]=c.z; Vs[kc*4+3][r]=c.w;
  }
  __syncthreads();
#pragma unroll
  for (int kk = 0; kk < GD; ++kk) {
    float4 ax = *reinterpret_cast<const float4*>(&Xs[kk][ty * 4]);
    float4 ay = *reinterpret_cast<const float4*>(&Ys[kk][ty * 4]);
    float4 bv = *reinterpret_cast<const float4*>(&Vs[kk][tx * 4]);
    float axv[4] = {ax.x, ax.y, ax.z, ax.w};
    float ayv[4] = {ay.x, ay.y, ay.z, ay.w};
    float bvv[4] = {bv.x, bv.y, bv.z, bv.w};
#pragma unroll
    for (int i = 0; i < 4; ++i)
#pragma unroll
      for (int j = 0; j < 4; ++j) {
        Sxg[i][j] = fmaf(axv[i], bvv[j], Sxg[i][j]);
        Syg[i][j] = fmaf(ayv[i], bvv[j], Syg[i][j]);
      }
  }

  float ep  = 1.f / (1.f + __expf(-p_eps[0]));
  float sg  = p_sig[0] * p_sig[0];
  float sg0 = p_sig0[0] * p_sig0[0];
  float cst = p_cst[0];
  float nis = -1.f / sg, nis0 = -1.f / sg0;
  float omep = 1.f - ep;
  float ss = 0.f;
  float colp[4] = {0.f, 0.f, 0.f, 0.f};
#pragma unroll
  for (int i = 0; i < 4; ++i) {
    float vout[4];
    float fx = fnX[ty*4+i], fy = fnY[ty*4+i];
    float gx = gnX[ty*4+i], gy = gnY[ty*4+i];
#pragma unroll
    for (int j = 0; j < 4; ++j) {
      float fv = fnV[tx*4+j], gv = gnV[tx*4+j];
      float dxf = fmaxf(fx + fv - 2.f * Sxf[i][j], 0.f);
      float dxg = fmaxf(gx + gv - 2.f * Sxg[i][j], 0.f);
      float dyf = fmaxf(fy + fv - 2.f * Syf[i][j], 0.f);
      float dyg = fmaxf(gy + gv - 2.f * Syg[i][j], 0.f);
      float kx = cst * (omep * __expf(dxf * nis0) + ep) * __expf(dxg * nis);
      float ky = cst * (omep * __expf(dyf * nis0) + ep) * __expf(dyg * nis);
      float fmv = (kx - ky) * 0.03125f;
      vout[j] = fmv;
      ss = fmaf(fmv, fmv, ss);
      colp[j] += fmv;
    }
    *reinterpret_cast<float4*>(&fm[(size_t)(i0 + ty * 4 + i) * NV + j0 + tx * 4]) =
        make_float4(vout[0], vout[1], vout[2], vout[3]);
  }
#pragma unroll
  for (int m = 32; m >= 1; m >>= 1) ss += __shfl_xor(ss, m);
  if ((tid & 63) == 0) ssred[tid >> 6] = ss;
#pragma unroll
  for (int j = 0; j < 4; ++j) red[ty][tx * 4 + j] = colp[j];
  __syncthreads();
  if (tid < 64) {
    float s = 0.f;
#pragma unroll
    for (int t = 0; t < 16; ++t) s += red[t][tid];
    atomicAdd(&colsum[j0 + tid], (double)s);
  }
  if (tid == 0) {
    double v = (double)ssred[0] + ssred[1] + ssred[2] + ssred[3];
    atomicAdd(&ss_parts[blockIdx.x & 63], v);
  }
}

__global__ __launch_bounds__(256) void mu_k(
    const double* __restrict__ colsum, float* __restrict__ mu,
    double* __restrict__ summu2)
{
  __shared__ double wred[4];
  double local = 0.0;
  for (int j = threadIdx.x; j < NV; j += 256) {
    double m = colsum[j] * (1.0 / (double)NXP);
    mu[j] = (float)m;
    local += m * m;
  }
  int lane = threadIdx.x & 63, wave = threadIdx.x >> 6;
#pragma unroll
  for (int m = 32; m >= 1; m >>= 1) local += __shfl_xor(local, m);
  if (lane == 0) wred[wave] = local;
  __syncthreads();
  if (threadIdx.x == 0) *summu2 = wred[0] + wred[1] + wred[2] + wred[3];
}

__global__ __launch_bounds__(256) void pass2_k(
    const float* __restrict__ fm, const float* __restrict__ mu,
    double* __restrict__ sz_parts)
{
  __shared__ float4 mus[NV / 4];
  for (int l = threadIdx.x; l < NV / 4; l += 256)
    mus[l] = reinterpret_cast<const float4*>(mu)[l];
  __syncthreads();
  __shared__ double zb[4];
  int wave = threadIdx.x >> 6, lane = threadIdx.x & 63;
  int row = blockIdx.x * 4 + wave;
  const float4* frow = reinterpret_cast<const float4*>(fm + (size_t)row * NV);
  float z = 0.f;
#pragma unroll
  for (int it = 0; it < 4; ++it) {
    float4 f = frow[lane + 64 * it];
    float4 m = mus[lane + 64 * it];
    z = fmaf(f.x, m.x, z); z = fmaf(f.y, m.y, z);
    z = fmaf(f.z, m.z, z); z = fmaf(f.w, m.w, z);
  }
#pragma unroll
  for (int m = 32; m >= 1; m >>= 1) z += __shfl_xor(z, m);
  if (lane == 0) zb[wave] = (double)z * (double)z;
  __syncthreads();
  if (threadIdx.x == 0)
    atomicAdd(&sz_parts[blockIdx.x & 63], zb[0] + zb[1] + zb[2] + zb[3]);
}

__global__ __launch_bounds__(64) void final_k(
    const double* __restrict__ ss_parts, const double* __restrict__ sz_parts,
    const double* __restrict__ summu2, float* __restrict__ out)
{
  int lane = threadIdx.x;
  double ss = ss_parts[lane], sz = sz_parts[lane];
#pragma unroll
  for (int m = 32; m >= 1; m >>= 1) { ss += __shfl_xor(ss, m); sz += __shfl_xor(sz, m); }
  if (lane == 0) {
    double smu2 = *summu2;
    const double nx = (double)NXP;
    double t1 = smu2 * nx / (nx - 1.0);
    double t2 = ss / (nx * (nx - 1.0));
    double um = t1 - t2;
    double uv = 4.0 * (sz / nx) - 4.0 * smu2 * smu2;
    out[0] = (float)(-(um / sqrt(uv + 1e-6)));
  }
}

// ---------------------------------------------------------------------------
extern "C" void kernel_launch(void* const* d_in, const int* in_sizes, int n_in,
                              void* d_out, int out_size, void* d_ws, size_t ws_size,
                              hipStream_t stream)
{
  (void)in_sizes; (void)n_in; (void)out_size; (void)ws_size;
  const float* XY = (const float*)d_in[0];
  const float* V  = (const float*)d_in[1];
  const float* dnW[6]; const float* dnb[6]; const float* anW[6]; const float* anb[6];
  for (int i = 0; i < 6; ++i) {
    dnW[i] = (const float*)d_in[2 + 2 * i];  dnb[i] = (const float*)d_in[3 + 2 * i];
    anW[i] = (const float*)d_in[14 + 2 * i]; anb[i] = (const float*)d_in[15 + 2 * i];
  }
  const float* p_eps  = (const float*)d_in[26];
  const float* p_sig  = (const float*)d_in[27];
  const float* p_sig0 = (const float*)d_in[28];
  const float* p_cst  = (const float*)d_in[29];

  char* base = (char*)d_ws;
  size_t off = 0;
  auto alloc = [&](size_t b) { size_t o = off; off += (b + 255) & ~(size_t)255; return o; };
  float* Xf    = (float*)(base + alloc((size_t)NROW * GD * 4));
  u16*   Xhi   = (u16*)  (base + alloc((size_t)NROW * 32 * 2));
  u16*   Xlo   = (u16*)  (base + alloc((size_t)NROW * 32 * 2));
  float* f_all = (float*)(base + alloc((size_t)NROW * FD * 4));
  float* g_all = (float*)(base + alloc((size_t)NROW * GD * 4));
  float* fn    = (float*)(base + alloc((size_t)NROW * 4));
  float* gn    = (float*)(base + alloc((size_t)NROW * 4));
  float* mu    = (float*)(base + alloc((size_t)NV * 4));
  size_t zoff = off;
  double* colsum   = (double*)(base + alloc(NV * 8));
  double* ss_parts = (double*)(base + alloc(64 * 8));
  double* sz_parts = (double*)(base + alloc(64 * 8));
  double* summu2   = (double*)(base + alloc(8));
  size_t zbytes = off - zoff;
  u16* Whi = (u16*)(base + alloc((size_t)12 * HP * HP * 2));
  u16* Wlo = (u16*)(base + alloc((size_t)12 * HP * HP * 2));
  float* fm = (float*)(base + alloc((size_t)NXP * NV * 4));

  hipMemsetAsync(base + zoff, 0, zbytes, stream);

  dim3 blk(256);
  prep_x<<<NROW * 32 / 256, blk, 0, stream>>>(XY, V, Xhi, Xlo, Xf);

  WAll wa;
  for (int i = 0; i < 6; ++i) {
    int K = (i == 0) ? GD : HD, M = (i == 5) ? FD : HD;
    int Kp = (i == 0) ? 32 : HP, Mp = (i == 5) ? 128 : HP;
    wa.d[i] = {dnW[i], Whi + (size_t)i * HP * HP, Wlo + (size_t)i * HP * HP, K, M, Kp, Mp};
  }
  for (int i = 0; i < 6; ++i) {
    int K = (i == 0) ? GD : HD, M = (i == 5) ? GD : HD;
    int Kp = (i == 0) ? 32 : HP, Mp = (i == 5) ? 64 : HP;
    wa.d[6 + i] = {anW[i], Whi + (size_t)(6 + i) * HP * HP, Wlo + (size_t)(6 + i) * HP * HP, K, M, Kp, Mp};
  }
  prep_w<<<dim3((HP * HP + 255) / 256, 12), blk, 0, stream>>>(wa);

  BiasAll bp;
  for (int i = 0; i < 6; ++i) { bp.b[i] = dnb[i]; bp.b[6 + i] = anb[i]; }

  mlp_fused<<<NROW / 32, dim3(128), 0, stream>>>(
      Xhi, Xlo, Xf, Whi, Wlo, bp, f_all, g_all);

  norms_k<<<NROW / 4, blk, 0, stream>>>(f_all, g_all, fn, gn);
  dist1_k<<<dim3(NXP / 64, NV / 64), blk, 0, stream>>>(
      f_all, g_all, fn, gn, p_eps, p_sig, p_sig0, p_cst, fm, colsum, ss_parts);
  mu_k<<<1, blk, 0, stream>>>(colsum, mu, summu2);
  pass2_k<<<NXP / 4, blk, 0, stream>>>(fm, mu, sz_parts);
  final_k<<<1, 64, 0, stream>>>(ss_parts, sz_parts, summu2, (float*)d_out);
}

// Round 5
// 1086.156 us; speedup vs baseline: 1.3049x; 1.3049x over previous
//
#include <hip/hip_runtime.h>
#include <cstdint>

#define NROW 66560   // 2*NX + J rows through both MLPs
#define NXP  32768   // nx
#define NV   1024    // J
#define FD   100     // dn output dim
#define GD   28      // input / an output dim
#define HD   300     // hidden dim
#define HP   320     // padded hidden dim
#define SAMP 48      // samples per block
#define ASTR 328     // LDS activation stride (u16): 164 words ≡ 4 mod 32 -> 2-way only

typedef unsigned short u16;
typedef __bf16 bf16x8 __attribute__((ext_vector_type(8)));
typedef float  f32x4  __attribute__((ext_vector_type(4)));

__device__ inline u16 f2bf(float x) {
  unsigned u = __builtin_bit_cast(unsigned, x);
  unsigned r = (u + 0x7FFF + ((u >> 16) & 1)) >> 16;
  return (u16)r;
}
__device__ inline float bf2f(u16 h) {
  unsigned u = ((unsigned)h) << 16;
  return __builtin_bit_cast(float, u);
}

// ---------------------------------------------------------------------------
// Prep: assemble [X;Y;V] rows, emit bf16 hi/lo planes (K padded 28->32) and
// fp32 copy (for the an-MLP residual).
// ---------------------------------------------------------------------------
__global__ __launch_bounds__(256) void prep_x(
    const float* __restrict__ XY, const float* __restrict__ V,
    u16* __restrict__ Xhi, u16* __restrict__ Xlo, float* __restrict__ Xf)
{
  int gid = blockIdx.x * 256 + threadIdx.x;   // NROW*32 total
  int row = gid >> 5, k = gid & 31;
  if (row >= NROW) return;
  float v = 0.f;
  if (k < GD) v = (row < 2 * NXP) ? XY[(size_t)row * GD + k]
                                  : V[(size_t)(row - 2 * NXP) * GD + k];
  u16 hi = f2bf(v);
  u16 lo = f2bf(v - bf2f(hi));
  Xhi[(size_t)row * 32 + k] = hi;
  Xlo[(size_t)row * 32 + k] = lo;
  if (k < GD) Xf[(size_t)row * GD + k] = v;
}

// ---------------------------------------------------------------------------
// Prep: transpose + split + zero-pad all 12 weight matrices. Wt[m][k] layout.
// ---------------------------------------------------------------------------
struct WDesc { const float* W; u16* hi; u16* lo; int K, M, Kpad, Mpad; };
struct WAll  { WDesc d[12]; };

__global__ __launch_bounds__(256) void prep_w(WAll wa)
{
  WDesc d = wa.d[blockIdx.y];
  int gid = blockIdx.x * 256 + threadIdx.x;
  if (gid >= d.Kpad * d.Mpad) return;
  int m = gid / d.Kpad, k = gid - m * d.Kpad;
  float v = (k < d.K && m < d.M) ? d.W[(size_t)k * d.M + m] : 0.f;
  u16 hi = f2bf(v);
  u16 lo = f2bf(v - bf2f(hi));
  d.hi[(size_t)m * d.Kpad + k] = hi;
  d.lo[(size_t)m * d.Kpad + k] = lo;
}

// ---------------------------------------------------------------------------
// Fused 12-layer MLP v2. 48 samples/block, 256 threads (4 waves).
// Wave w owns an 80-feature strip (MT=5) x all 48 samples (NT=3).
// A-operand = weights: global->reg (L2-resident, no LDS, no k-loop barriers).
// B-operand = activations: LDS hi/lo planes (61.5 KB total -> 2 blocks/CU).
// Layer 0/6 B-fragments come straight from global Xhi/Xlo (no input LDS).
// 3 MFMAs per product (bf16x3: Wh*Ah + Wl*Ah + Wh*Al).
// ---------------------------------------------------------------------------
struct BiasAll { const float* b[12]; };

template<int MT, int KCH>
__device__ __forceinline__ void mm_lds(
    const u16* __restrict__ Wh, const u16* __restrict__ Wl,
    const u16* aH, const u16* aL,
    f32x4 (&acc)[MT][3], int featbase, int m16, int quad)
{
#pragma unroll
  for (int mt = 0; mt < MT; ++mt)
#pragma unroll
    for (int nt = 0; nt < 3; ++nt) acc[mt][nt] = (f32x4)0.f;
#pragma unroll 2
  for (int ch = 0; ch < KCH; ++ch) {
    const int k0 = ch * 32 + quad * 8;
    bf16x8 bh[3], bl[3];
#pragma unroll
    for (int nt = 0; nt < 3; ++nt) {
      bh[nt] = *reinterpret_cast<const bf16x8*>(&aH[(nt * 16 + m16) * ASTR + k0]);
      bl[nt] = *reinterpret_cast<const bf16x8*>(&aL[(nt * 16 + m16) * ASTR + k0]);
    }
#pragma unroll
    for (int mt = 0; mt < MT; ++mt) {
      size_t wo = (size_t)(featbase + mt * 16) * HP + k0;
      bf16x8 ah = *reinterpret_cast<const bf16x8*>(&Wh[wo]);
      bf16x8 al = *reinterpret_cast<const bf16x8*>(&Wl[wo]);
#pragma unroll
      for (int nt = 0; nt < 3; ++nt) {
        acc[mt][nt] = __builtin_amdgcn_mfma_f32_16x16x32_bf16(ah, bh[nt], acc[mt][nt], 0, 0, 0);
        acc[mt][nt] = __builtin_amdgcn_mfma_f32_16x16x32_bf16(al, bh[nt], acc[mt][nt], 0, 0, 0);
        acc[mt][nt] = __builtin_amdgcn_mfma_f32_16x16x32_bf16(ah, bl[nt], acc[mt][nt], 0, 0, 0);
      }
    }
  }
}

template<int MT>
__device__ __forceinline__ void mm_in(
    const u16* __restrict__ Wh, const u16* __restrict__ Wl,
    const u16* __restrict__ Xhi, const u16* __restrict__ Xlo, int row0,
    f32x4 (&acc)[MT][3], int featbase, int m16, int quad)
{
#pragma unroll
  for (int mt = 0; mt < MT; ++mt)
#pragma unroll
    for (int nt = 0; nt < 3; ++nt) acc[mt][nt] = (f32x4)0.f;
  const int k0 = quad * 8;
  bf16x8 bh[3], bl[3];
#pragma unroll
  for (int nt = 0; nt < 3; ++nt) {
    bh[nt] = *reinterpret_cast<const bf16x8*>(&Xhi[(size_t)(row0 + nt * 16 + m16) * 32 + k0]);
    bl[nt] = *reinterpret_cast<const bf16x8*>(&Xlo[(size_t)(row0 + nt * 16 + m16) * 32 + k0]);
  }
#pragma unroll
  for (int mt = 0; mt < MT; ++mt) {
    size_t wo = (size_t)(featbase + mt * 16) * 32 + k0;
    bf16x8 ah = *reinterpret_cast<const bf16x8*>(&Wh[wo]);
    bf16x8 al = *reinterpret_cast<const bf16x8*>(&Wl[wo]);
#pragma unroll
    for (int nt = 0; nt < 3; ++nt) {
      acc[mt][nt] = __builtin_amdgcn_mfma_f32_16x16x32_bf16(ah, bh[nt], acc[mt][nt], 0, 0, 0);
      acc[mt][nt] = __builtin_amdgcn_mfma_f32_16x16x32_bf16(al, bh[nt], acc[mt][nt], 0, 0, 0);
      acc[mt][nt] = __builtin_amdgcn_mfma_f32_16x16x32_bf16(ah, bl[nt], acc[mt][nt], 0, 0, 0);
    }
  }
}

template<int MT>
__device__ __forceinline__ void epi_lds(
    f32x4 (&acc)[MT][3], const float* __restrict__ bias,
    u16* aH, u16* aL, int ftile0, int m16, int quad)
{
#pragma unroll
  for (int mt = 0; mt < MT; ++mt) {
    int featb = ftile0 + mt * 16 + quad * 4;
#pragma unroll
    for (int nt = 0; nt < 3; ++nt) {
      int samp = nt * 16 + m16;
      ushort4 h4, l4;
#pragma unroll
      for (int r = 0; r < 4; ++r) {
        int feat = featb + r;
        float x = acc[mt][nt][r] + (feat < HD ? bias[feat] : 0.f);
        x = fmaxf(x, 0.f);
        u16 h = f2bf(x);
        u16 l = f2bf(x - bf2f(h));
        reinterpret_cast<u16*>(&h4)[r] = h;
        reinterpret_cast<u16*>(&l4)[r] = l;
      }
      *reinterpret_cast<ushort4*>(&aH[samp * ASTR + featb]) = h4;
      *reinterpret_cast<ushort4*>(&aL[samp * ASTR + featb]) = l4;
    }
  }
}

__global__ __launch_bounds__(256, 2) void mlp_fused(
    const u16* __restrict__ Xhi, const u16* __restrict__ Xlo,
    const float* __restrict__ Xf,
    const u16* __restrict__ Whi, const u16* __restrict__ Wlo,
    BiasAll bp, float* __restrict__ f_all, float* __restrict__ g_all)
{
  __shared__ u16 aH[SAMP * ASTR], aL[SAMP * ASTR];
  const int tid  = threadIdx.x;
  const int wave = tid >> 6, lane = tid & 63;
  const int m16  = lane & 15, quad = lane >> 4;
  const int row0 = (blockIdx.x * SAMP + SAMP <= NROW) ? blockIdx.x * SAMP
                                                      : NROW - SAMP;  // overlap-safe

  auto W = [&](int s) { return Whi + (size_t)s * HP * HP; };
  auto Lw = [&](int s) { return Wlo + (size_t)s * HP * HP; };

  // ---- dn MLP ----
  {
    f32x4 acc[5][3];
    mm_in<5>(W(0), Lw(0), Xhi, Xlo, row0, acc, wave * 80 + m16, m16, quad);
    epi_lds<5>(acc, bp.b[0], aH, aL, wave * 80, m16, quad);  // first LDS write
  }
  __syncthreads();
#pragma unroll 1
  for (int s = 1; s <= 4; ++s) {
    f32x4 acc[5][3];
    mm_lds<5, 10>(W(s), Lw(s), aH, aL, acc, wave * 80 + m16, m16, quad);
    __syncthreads();   // all reads of aH/aL done
    epi_lds<5>(acc, bp.b[s], aH, aL, wave * 80, m16, quad);
    __syncthreads();   // writes visible
  }
  {
    f32x4 acc[2][3];
    mm_lds<2, 10>(W(5), Lw(5), aH, aL, acc, wave * 32 + m16, m16, quad);
    const float* b5 = bp.b[5];
#pragma unroll
    for (int mt = 0; mt < 2; ++mt) {
      int c = wave * 32 + mt * 16 + quad * 4;
      if (c < FD) {
#pragma unroll
        for (int nt = 0; nt < 3; ++nt) {
          int samp = nt * 16 + m16;
          float4 v;
          v.x = acc[mt][nt][0] + b5[c + 0];
          v.y = acc[mt][nt][1] + b5[c + 1];
          v.z = acc[mt][nt][2] + b5[c + 2];
          v.w = acc[mt][nt][3] + b5[c + 3];
          *reinterpret_cast<float4*>(&f_all[(size_t)(row0 + samp) * FD + c]) = v;
        }
      }
    }
  }
  __syncthreads();   // layer-5 reads of aH/aL complete before overwrite

  // ---- an MLP ----
  {
    f32x4 acc[5][3];
    mm_in<5>(W(6), Lw(6), Xhi, Xlo, row0, acc, wave * 80 + m16, m16, quad);
    epi_lds<5>(acc, bp.b[6], aH, aL, wave * 80, m16, quad);
  }
  __syncthreads();
#pragma unroll 1
  for (int s = 7; s <= 10; ++s) {
    f32x4 acc[5][3];
    mm_lds<5, 10>(W(s), Lw(s), aH, aL, acc, wave * 80 + m16, m16, quad);
    __syncthreads();
    epi_lds<5>(acc, bp.b[s], aH, aL, wave * 80, m16, quad);
    __syncthreads();
  }
  {
    f32x4 acc[1][3];
    mm_lds<1, 10>(W(11), Lw(11), aH, aL, acc, wave * 16 + m16, m16, quad);
    const float* b11 = bp.b[11];
    int c = wave * 16 + quad * 4;
    if (c < GD) {
#pragma unroll
      for (int nt = 0; nt < 3; ++nt) {
        int samp = nt * 16 + m16;
        float4 rv = *reinterpret_cast<const float4*>(&Xf[(size_t)(row0 + samp) * GD + c]);
        float4 v;
        v.x = acc[0][nt][0] + b11[c + 0] + rv.x;
        v.y = acc[0][nt][1] + b11[c + 1] + rv.y;
        v.z = acc[0][nt][2] + b11[c + 2] + rv.z;
        v.w = acc[0][nt][3] + b11[c + 3] + rv.w;
        *reinterpret_cast<float4*>(&g_all[(size_t)(row0 + samp) * GD + c]) = v;
      }
    }
  }
}

// ---------------------------------------------------------------------------
// Row squared-norms of f_all (100 dims) and g_all (28 dims). One wave per row.
// ---------------------------------------------------------------------------
__global__ __launch_bounds__(256) void norms_k(
    const float* __restrict__ f_all, const float* __restrict__ g_all,
    float* __restrict__ fn, float* __restrict__ gn)
{
  int wave = threadIdx.x >> 6, lane = threadIdx.x & 63;
  int row = blockIdx.x * 4 + wave;
  const float* f = f_all + (size_t)row * FD;
  const float* g = g_all + (size_t)row * GD;
  float s = f[lane] * f[lane];
  if (lane < FD - 64) { float t = f[lane + 64]; s += t * t; }
  float sg = 0.f;
  if (lane < GD) { float t = g[lane]; sg = t * t; }
#pragma unroll
  for (int m = 32; m >= 1; m >>= 1) { s += __shfl_xor(s, m); sg += __shfl_xor(sg, m); }
  if (lane == 0) { fn[row] = s; gn[row] = sg; }
}

// ---------------------------------------------------------------------------
// Pass 1: fused pdist2 + kernel + fm write + colsum/ss partial reductions.
// ---------------------------------------------------------------------------
__global__ __launch_bounds__(256) void dist1_k(
    const float* __restrict__ f_all, const float* __restrict__ g_all,
    const float* __restrict__ fn, const float* __restrict__ gn,
    const float* __restrict__ p_eps, const float* __restrict__ p_sig,
    const float* __restrict__ p_sig0, const float* __restrict__ p_cst,
    float* __restrict__ fm, double* __restrict__ colsum,
    double* __restrict__ ss_parts)
{
  __shared__ float Xs[GD][68], Ys[GD][68], Vs[GD][68];
  __shared__ float fnX[64], fnY[64], fnV[64], gnX[64], gnY[64], gnV[64];
  __shared__ float red[16][68];
  __shared__ float ssred[4];
  const int tid = threadIdx.x;
  const int tx = tid & 15, ty = tid >> 4;
  const int i0 = blockIdx.x * 64, j0 = blockIdx.y * 64;

  if (tid < 64) {
    fnX[tid] = fn[i0 + tid]; fnY[tid] = fn[NXP + i0 + tid]; fnV[tid] = fn[2 * NXP + j0 + tid];
    gnX[tid] = gn[i0 + tid]; gnY[tid] = gn[NXP + i0 + tid]; gnV[tid] = gn[2 * NXP + j0 + tid];
  }

  float Sxf[4][4] = {}, Syf[4][4] = {}, Sxg[4][4] = {}, Syg[4][4] = {};
  const float* fX = f_all;
  const float* fY = f_all + (size_t)NXP * FD;
  const float* fV = f_all + (size_t)2 * NXP * FD;
  const float* gX = g_all;
  const float* gY = g_all + (size_t)NXP * GD;
  const float* gV = g_all + (size_t)2 * NXP * GD;

  for (int k0 = 0; k0 < FD; k0 += 20) {
    __syncthreads();
    for (int l = tid; l < 320; l += 256) {
      int r = l / 5, kc = l % 5;
      float4 a = *reinterpret_cast<const float4*>(&fX[(size_t)(i0 + r) * FD + k0 + kc * 4]);
      float4 b = *reinterpret_cast<const float4*>(&fY[(size_t)(i0 + r) * FD + k0 + kc * 4]);
      float4 c = *reinterpret_cast<const float4*>(&fV[(size_t)(j0 + r) * FD + k0 + kc * 4]);
      Xs[kc*4+0][r]=a.x; Xs[kc*4+1][r]=a.y; Xs[kc*4+2][r]=a.z; Xs[kc*4+3][r]=a.w;
      Ys[kc*4+0][r]=b.x; Ys[kc*4+1][r]=b.y; Ys[kc*4+2][r]=b.z; Ys[kc*4+3][r]=b.w;
      Vs[kc*4+0][r]=c.x; Vs[kc*4+1][r]=c.y; Vs[kc*4+2][r]=c.z; Vs[kc*4+3][r]=c.w;
    }
    __syncthreads();
#pragma unroll
    for (int kk = 0; kk < 20; ++kk) {
      float4 ax = *reinterpret_cast<const float4*>(&Xs[kk][ty * 4]);
      float4 ay = *reinterpret_cast<const float4*>(&Ys[kk][ty * 4]);
      float4 bv = *reinterpret_cast<const float4*>(&Vs[kk][tx * 4]);
      float axv[4] = {ax.x, ax.y, ax.z, ax.w};
      float ayv[4] = {ay.x, ay.y, ay.z, ay.w};
      float bvv[4] = {bv.x, bv.y, bv.z, bv.w};
#pragma unroll
      for (int i = 0; i < 4; ++i)
#pragma unroll
        for (int j = 0; j < 4; ++j) {
          Sxf[i][j] = fmaf(axv[i], bvv[j], Sxf[i][j]);
          Syf[i][j] = fmaf(ayv[i], bvv[j], Syf[i][j]);
        }
    }
  }

  __syncthreads();
  for (int l = tid; l < 448; l += 256) {
    int r = l / 7, kc = l % 7;
    float4 a = *reinterpret_cast<const float4*>(&gX[(size_t)(i0 + r) * GD + kc * 4]);
    float4 b = *reinterpret_cast<const float4*>(&gY[(size_t)(i0 + r) * GD + kc * 4]);
    float4 c = *reinterpret_cast<const float4*>(&gV[(size_t)(j0 + r) * GD + kc * 4]);
    Xs[kc*4+0][r]=a.x; Xs[kc*4+1][r]=a.y; Xs[kc*4+2][r]=a.z; Xs[kc*4+3][r]=a.w;
    Ys[kc*4+0][r]=b.x; Ys[kc*4+1][r]=b.y; Ys[kc*4+2][r]=b.z; Ys[kc*4+3][r]=b.w;
    Vs[kc*4+0][r]=c.x; Vs[kc*4+1][r]=c.y; Vs[kc*4+2][r]=c.z; Vs[kc*4+3][r]=c.w;
  }
  __syncthreads();
#pragma unroll
  for (int kk = 0; kk < GD; ++kk) {
    float4 ax = *reinterpret_cast<const float4*>(&Xs[kk][ty * 4]);
    float4 ay = *reinterpret_cast<const float4*>(&Ys[kk][ty * 4]);
    float4 bv = *reinterpret_cast<const float4*>(&Vs[kk][tx * 4]);
    float axv[4] = {ax.x, ax.y, ax.z, ax.w};
    float ayv[4] = {ay.x, ay.y, ay.z, ay.w};
    float bvv[4] = {bv.x, bv.y, bv.z, bv.w};
#pragma unroll
    for (int i = 0; i < 4; ++i)
#pragma unroll
      for (int j = 0; j < 4; ++j) {
        Sxg[i][j] = fmaf(axv[i], bvv[j], Sxg[i][j]);
        Syg[i][j] = fmaf(ayv[i], bvv[j], Syg[i][j]);
      }
  }

  float ep  = 1.f / (1.f + __expf(-p_eps[0]));
  float sg  = p_sig[0] * p_sig[0];
  float sg0 = p_sig0[0] * p_sig0[0];
  float cst = p_cst[0];
  float nis = -1.f / sg, nis0 = -1.f / sg0;
  float omep = 1.f - ep;
  float ss = 0.f;
  float colp[4] = {0.f, 0.f, 0.f, 0.f};
#pragma unroll
  for (int i = 0; i < 4; ++i) {
    float vout[4];
    float fx = fnX[ty*4+i], fy = fnY[ty*4+i];
    float gx = gnX[ty*4+i], gy = gnY[ty*4+i];
#pragma unroll
    for (int j = 0; j < 4; ++j) {
      float fv = fnV[tx*4+j], gv = gnV[tx*4+j];
      float dxf = fmaxf(fx + fv - 2.f * Sxf[i][j], 0.f);
      float dxg = fmaxf(gx + gv - 2.f * Sxg[i][j], 0.f);
      float dyf = fmaxf(fy + fv - 2.f * Syf[i][j], 0.f);
      float dyg = fmaxf(gy + gv - 2.f * Syg[i][j], 0.f);
      float kx = cst * (omep * __expf(dxf * nis0) + ep) * __expf(dxg * nis);
      float ky = cst * (omep * __expf(dyf * nis0) + ep) * __expf(dyg * nis);
      float fmv = (kx - ky) * 0.03125f;
      vout[j] = fmv;
      ss = fmaf(fmv, fmv, ss);
      colp[j] += fmv;
    }
    *reinterpret_cast<float4*>(&fm[(size_t)(i0 + ty * 4 + i) * NV + j0 + tx * 4]) =
        make_float4(vout[0], vout[1], vout[2], vout[3]);
  }
#pragma unroll
  for (int m = 32; m >= 1; m >>= 1) ss += __shfl_xor(ss, m);
  if ((tid & 63) == 0) ssred[tid >> 6] = ss;
#pragma unroll
  for (int j = 0; j < 4; ++j) red[ty][tx * 4 + j] = colp[j];
  __syncthreads();
  if (tid < 64) {
    float s = 0.f;
#pragma unroll
    for (int t = 0; t < 16; ++t) s += red[t][tid];
    atomicAdd(&colsum[j0 + tid], (double)s);
  }
  if (tid == 0) {
    double v = (double)ssred[0] + ssred[1] + ssred[2] + ssred[3];
    atomicAdd(&ss_parts[blockIdx.x & 63], v);
  }
}

__global__ __launch_bounds__(256) void mu_k(
    const double* __restrict__ colsum, float* __restrict__ mu,
    double* __restrict__ summu2)
{
  __shared__ double wred[4];
  double local = 0.0;
  for (int j = threadIdx.x; j < NV; j += 256) {
    double m = colsum[j] * (1.0 / (double)NXP);
    mu[j] = (float)m;
    local += m * m;
  }
  int lane = threadIdx.x & 63, wave = threadIdx.x >> 6;
#pragma unroll
  for (int m = 32; m >= 1; m >>= 1) local += __shfl_xor(local, m);
  if (lane == 0) wred[wave] = local;
  __syncthreads();
  if (threadIdx.x == 0) *summu2 = wred[0] + wred[1] + wred[2] + wred[3];
}

__global__ __launch_bounds__(256) void pass2_k(
    const float* __restrict__ fm, const float* __restrict__ mu,
    double* __restrict__ sz_parts)
{
  __shared__ float4 mus[NV / 4];
  for (int l = threadIdx.x; l < NV / 4; l += 256)
    mus[l] = reinterpret_cast<const float4*>(mu)[l];
  __syncthreads();
  __shared__ double zb[4];
  int wave = threadIdx.x >> 6, lane = threadIdx.x & 63;
  int row = blockIdx.x * 4 + wave;
  const float4* frow = reinterpret_cast<const float4*>(fm + (size_t)row * NV);
  float z = 0.f;
#pragma unroll
  for (int it = 0; it < 4; ++it) {
    float4 f = frow[lane + 64 * it];
    float4 m = mus[lane + 64 * it];
    z = fmaf(f.x, m.x, z); z = fmaf(f.y, m.y, z);
    z = fmaf(f.z, m.z, z); z = fmaf(f.w, m.w, z);
  }
#pragma unroll
  for (int m = 32; m >= 1; m >>= 1) z += __shfl_xor(z, m);
  if (lane == 0) zb[wave] = (double)z * (double)z;
  __syncthreads();
  if (threadIdx.x == 0)
    atomicAdd(&sz_parts[blockIdx.x & 63], zb[0] + zb[1] + zb[2] + zb[3]);
}

__global__ __launch_bounds__(64) void final_k(
    const double* __restrict__ ss_parts, const double* __restrict__ sz_parts,
    const double* __restrict__ summu2, float* __restrict__ out)
{
  int lane = threadIdx.x;
  double ss = ss_parts[lane], sz = sz_parts[lane];
#pragma unroll
  for (int m = 32; m >= 1; m >>= 1) { ss += __shfl_xor(ss, m); sz += __shfl_xor(sz, m); }
  if (lane == 0) {
    double smu2 = *summu2;
    const double nx = (double)NXP;
    double t1 = smu2 * nx / (nx - 1.0);
    double t2 = ss / (nx * (nx - 1.0));
    double um = t1 - t2;
    double uv = 4.0 * (sz / nx) - 4.0 * smu2 * smu2;
    out[0] = (float)(-(um / sqrt(uv + 1e-6)));
  }
}

// ---------------------------------------------------------------------------
extern "C" void kernel_launch(void* const* d_in, const int* in_sizes, int n_in,
                              void* d_out, int out_size, void* d_ws, size_t ws_size,
                              hipStream_t stream)
{
  (void)in_sizes; (void)n_in; (void)out_size; (void)ws_size;
  const float* XY = (const float*)d_in[0];
  const float* V  = (const float*)d_in[1];
  const float* dnW[6]; const float* dnb[6]; const float* anW[6]; const float* anb[6];
  for (int i = 0; i < 6; ++i) {
    dnW[i] = (const float*)d_in[2 + 2 * i];  dnb[i] = (const float*)d_in[3 + 2 * i];
    anW[i] = (const float*)d_in[14 + 2 * i]; anb[i] = (const float*)d_in[15 + 2 * i];
  }
  const float* p_eps  = (const float*)d_in[26];
  const float* p_sig  = (const float*)d_in[27];
  const float* p_sig0 = (const float*)d_in[28];
  const float* p_cst  = (const float*)d_in[29];

  char* base = (char*)d_ws;
  size_t off = 0;
  auto alloc = [&](size_t b) { size_t o = off; off += (b + 255) & ~(size_t)255; return o; };
  float* Xf    = (float*)(base + alloc((size_t)NROW * GD * 4));
  u16*   Xhi   = (u16*)  (base + alloc((size_t)NROW * 32 * 2));
  u16*   Xlo   = (u16*)  (base + alloc((size_t)NROW * 32 * 2));
  float* f_all = (float*)(base + alloc((size_t)NROW * FD * 4));
  float* g_all = (float*)(base + alloc((size_t)NROW * GD * 4));
  float* fn    = (float*)(base + alloc((size_t)NROW * 4));
  float* gn    = (float*)(base + alloc((size_t)NROW * 4));
  float* mu    = (float*)(base + alloc((size_t)NV * 4));
  size_t zoff = off;
  double* colsum   = (double*)(base + alloc(NV * 8));
  double* ss_parts = (double*)(base + alloc(64 * 8));
  double* sz_parts = (double*)(base + alloc(64 * 8));
  double* summu2   = (double*)(base + alloc(8));
  size_t zbytes = off - zoff;
  u16* Whi = (u16*)(base + alloc((size_t)12 * HP * HP * 2));
  u16* Wlo = (u16*)(base + alloc((size_t)12 * HP * HP * 2));
  float* fm = (float*)(base + alloc((size_t)NXP * NV * 4));

  hipMemsetAsync(base + zoff, 0, zbytes, stream);

  dim3 blk(256);
  prep_x<<<NROW * 32 / 256, blk, 0, stream>>>(XY, V, Xhi, Xlo, Xf);

  WAll wa;
  for (int i = 0; i < 6; ++i) {
    int K = (i == 0) ? GD : HD, M = (i == 5) ? FD : HD;
    int Kp = (i == 0) ? 32 : HP, Mp = (i == 5) ? 128 : HP;
    wa.d[i] = {dnW[i], Whi + (size_t)i * HP * HP, Wlo + (size_t)i * HP * HP, K, M, Kp, Mp};
  }
  for (int i = 0; i < 6; ++i) {
    int K = (i == 0) ? GD : HD, M = (i == 5) ? GD : HD;
    int Kp = (i == 0) ? 32 : HP, Mp = (i == 5) ? 64 : HP;
    wa.d[6 + i] = {anW[i], Whi + (size_t)(6 + i) * HP * HP, Wlo + (size_t)(6 + i) * HP * HP, K, M, Kp, Mp};
  }
  prep_w<<<dim3((HP * HP + 255) / 256, 12), blk, 0, stream>>>(wa);

  BiasAll bp;
  for (int i = 0; i < 6; ++i) { bp.b[i] = dnb[i]; bp.b[6 + i] = anb[i]; }

  const int nblk = (NROW + SAMP - 1) / SAMP;  // 1387, last block overlaps (idempotent)
  mlp_fused<<<nblk, blk, 0, stream>>>(Xhi, Xlo, Xf, Whi, Wlo, bp, f_all, g_all);

  norms_k<<<NROW / 4, blk, 0, stream>>>(f_all, g_all, fn, gn);
  dist1_k<<<dim3(NXP / 64, NV / 64), blk, 0, stream>>>(
      f_all, g_all, fn, gn, p_eps, p_sig, p_sig0, p_cst, fm, colsum, ss_parts);
  mu_k<<<1, blk, 0, stream>>>(colsum, mu, summu2);
  pass2_k<<<NXP / 4, blk, 0, stream>>>(fm, mu, sz_parts);
  final_k<<<1, 64, 0, stream>>>(ss_parts, sz_parts, summu2, (float*)d_out);
}